// Round 1
// baseline (204.195 us; speedup 1.0000x reference)
//
#include <hip/hip_runtime.h>
#include <math.h>

#define NB 64
#define V_FULL 6890
#define V_HAND 250
#define V_LOOP 20
#define N_FACES 500
#define NPTS 251  // V_HAND + 1 (appended loop-mean vertex)

// One block per (batch, direction).
// dir 0: points = left-hand verts, other = right-hand verts, faces = faces_right
// dir 1: points = right-hand verts, other = left-hand verts,  faces = faces_left
__global__ __launch_bounds__(256) void hand_pen_kernel(
    const float* __restrict__ verts,     // [NB][V_FULL][3]
    const int* __restrict__ inds_l,      // [V_HAND]
    const int* __restrict__ inds_r,      // [V_HAND]
    const int* __restrict__ loop_l,      // [V_LOOP]
    const int* __restrict__ loop_r,      // [V_LOOP]
    const int* __restrict__ faces_l,     // [N_FACES][3]
    const int* __restrict__ faces_r,     // [N_FACES][3]
    float* __restrict__ partial)         // [NB][2]
{
    const int b   = blockIdx.x;
    const int dir = blockIdx.y;
    const int tid = threadIdx.x;

    __shared__ float pts[NPTS][3];   // query points
    __shared__ float ov[NPTS][3];    // other-hand verts
    __shared__ int   fc[N_FACES * 3];
    __shared__ float wave_part[4];

    const float* vb = verts + (size_t)b * V_FULL * 3;
    const int* pind  = (dir == 0) ? inds_l  : inds_r;
    const int* oind  = (dir == 0) ? inds_r  : inds_l;
    const int* ploop = (dir == 0) ? loop_l  : loop_r;
    const int* oloop = (dir == 0) ? loop_r  : loop_l;
    const int* fcs   = (dir == 0) ? faces_r : faces_l;

    // Gather the two 250-vertex hand sets into LDS
    for (int i = tid; i < V_HAND; i += 256) {
        int gp = pind[i];
        pts[i][0] = vb[gp * 3 + 0];
        pts[i][1] = vb[gp * 3 + 1];
        pts[i][2] = vb[gp * 3 + 2];
        int go = oind[i];
        ov[i][0] = vb[go * 3 + 0];
        ov[i][1] = vb[go * 3 + 1];
        ov[i][2] = vb[go * 3 + 2];
    }
    // Appended vertex 250 = mean of the 20 loop verts
    if (tid < 2) {
        const int* lp = (tid == 0) ? ploop : oloop;
        float sx = 0.f, sy = 0.f, sz = 0.f;
        for (int i = 0; i < V_LOOP; ++i) {
            int gi = lp[i];
            sx += vb[gi * 3 + 0];
            sy += vb[gi * 3 + 1];
            sz += vb[gi * 3 + 2];
        }
        const float inv = 1.0f / (float)V_LOOP;
        if (tid == 0) {
            pts[V_HAND][0] = sx * inv; pts[V_HAND][1] = sy * inv; pts[V_HAND][2] = sz * inv;
        } else {
            ov[V_HAND][0] = sx * inv; ov[V_HAND][1] = sy * inv; ov[V_HAND][2] = sz * inv;
        }
    }
    for (int i = tid; i < N_FACES * 3; i += 256) fc[i] = fcs[i];
    __syncthreads();

    float contrib = 0.0f;
    if (tid < NPTS) {
        const float px = pts[tid][0], py = pts[tid][1], pz = pts[tid][2];

        // Winding number: omega = sum_f 2*atan2(det, denom); w = omega/(4pi)
        // inside <=> w > 0.5 <=> sum_f atan2(det, denom) > pi
        float wsum = 0.0f;
        for (int f = 0; f < N_FACES; ++f) {
            int i0 = fc[f * 3 + 0], i1 = fc[f * 3 + 1], i2 = fc[f * 3 + 2];
            float ax = ov[i0][0] - px, ay = ov[i0][1] - py, az = ov[i0][2] - pz;
            float bx = ov[i1][0] - px, by = ov[i1][1] - py, bz = ov[i1][2] - pz;
            float cx = ov[i2][0] - px, cy = ov[i2][1] - py, cz = ov[i2][2] - pz;

            float la = sqrtf(ax * ax + ay * ay + az * az);
            float lb = sqrtf(bx * bx + by * by + bz * bz);
            float lc = sqrtf(cx * cx + cy * cy + cz * cz);

            // u = b x c
            float ux = by * cz - bz * cy;
            float uy = bz * cx - bx * cz;
            float uz = bx * cy - by * cx;
            float det = ax * ux + ay * uy + az * uz;

            float ab = ax * bx + ay * by + az * bz;
            float bc = bx * cx + by * cy + bz * cz;
            float ca = cx * ax + cy * ay + cz * az;

            float denom = la * lb * lc + ab * lc + bc * la + ca * lb;
            wsum += atan2f(det, denom);
        }

        // Min distance to the other hand's 251 verts
        float d2min = 1e30f;
        for (int j = 0; j < NPTS; ++j) {
            float dx = ov[j][0] - px, dy = ov[j][1] - py, dz = ov[j][2] - pz;
            float d2 = dx * dx + dy * dy + dz * dz;
            d2min = fminf(d2min, d2);
        }
        float depth = sqrtf(d2min + 1e-12f);
        contrib = (wsum > (float)M_PI) ? depth : 0.0f;
    }

    // Block reduction: wave64 shuffle then 4 partials in LDS
    for (int off = 32; off > 0; off >>= 1)
        contrib += __shfl_down(contrib, off);
    if ((tid & 63) == 0) wave_part[tid >> 6] = contrib;
    __syncthreads();
    if (tid == 0)
        partial[b * 2 + dir] = wave_part[0] + wave_part[1] + wave_part[2] + wave_part[3];
}

__global__ void combine_kernel(const float* __restrict__ partial, float* __restrict__ out)
{
    int i = threadIdx.x;
    if (i < NB) out[i] = partial[i * 2 + 0] + partial[i * 2 + 1];
}

extern "C" void kernel_launch(void* const* d_in, const int* in_sizes, int n_in,
                              void* d_out, int out_size, void* d_ws, size_t ws_size,
                              hipStream_t stream) {
    const float* verts  = (const float*)d_in[0];
    const int* inds_l   = (const int*)d_in[1];
    const int* inds_r   = (const int*)d_in[2];
    const int* loop_l   = (const int*)d_in[3];
    const int* loop_r   = (const int*)d_in[4];
    const int* faces_l  = (const int*)d_in[5];
    const int* faces_r  = (const int*)d_in[6];
    float* out = (float*)d_out;
    float* partial = (float*)d_ws;  // NB*2 floats

    hand_pen_kernel<<<dim3(NB, 2), 256, 0, stream>>>(
        verts, inds_l, inds_r, loop_l, loop_r, faces_l, faces_r, partial);
    combine_kernel<<<1, 64, 0, stream>>>(partial, out);
}

// Round 2
// 76.274 us; speedup vs baseline: 2.6771x; 2.6771x over previous
//
#include <hip/hip_runtime.h>
#include <math.h>

#define NB 64
#define V_FULL 6890
#define V_HAND 250
#define V_LOOP 20
#define N_FACES 500
#define NPTS 251      // V_HAND + 1 (appended loop-mean vertex)
#define KSPLIT 8      // lanes per point (face-loop split)
#define PCHUNK 32     // points per block
#define NCHUNK 8      // ceil(251/32)

// Grid (NB, 2, NCHUNK). Block 256 = PCHUNK points x KSPLIT lanes.
// dir 0: points = left-hand verts, other = right, faces = faces_right
// dir 1: points = right-hand verts, other = left,  faces = faces_left
__global__ __launch_bounds__(256) void hand_pen_kernel(
    const float* __restrict__ verts,     // [NB][V_FULL][3]
    const int* __restrict__ inds_l,
    const int* __restrict__ inds_r,
    const int* __restrict__ loop_l,
    const int* __restrict__ loop_r,
    const int* __restrict__ faces_l,     // [N_FACES][3]
    const int* __restrict__ faces_r,
    float* __restrict__ partial)         // [NB][2][NCHUNK]
{
    const int b    = blockIdx.x;
    const int dir  = blockIdx.y;
    const int z    = blockIdx.z;
    const int tid  = threadIdx.x;
    const int lp   = tid >> 3;          // local point 0..31
    const int k    = tid & 7;           // face-split lane 0..7
    const int p    = z * PCHUNK + lp;   // global point index

    __shared__ float pts[NPTS][3];
    __shared__ float ov[NPTS][3];
    __shared__ int   fc[N_FACES * 3];
    __shared__ float wave_part[4];

    const float* vb = verts + (size_t)b * V_FULL * 3;
    const int* pind  = (dir == 0) ? inds_l  : inds_r;
    const int* oind  = (dir == 0) ? inds_r  : inds_l;
    const int* ploop = (dir == 0) ? loop_l  : loop_r;
    const int* oloop = (dir == 0) ? loop_r  : loop_l;
    const int* fcs   = (dir == 0) ? faces_r : faces_l;

    for (int i = tid; i < V_HAND; i += 256) {
        int gp = pind[i];
        pts[i][0] = vb[gp * 3 + 0];
        pts[i][1] = vb[gp * 3 + 1];
        pts[i][2] = vb[gp * 3 + 2];
        int go = oind[i];
        ov[i][0] = vb[go * 3 + 0];
        ov[i][1] = vb[go * 3 + 1];
        ov[i][2] = vb[go * 3 + 2];
    }
    if (tid < 2) {
        const int* lpv = (tid == 0) ? ploop : oloop;
        float sx = 0.f, sy = 0.f, sz = 0.f;
        for (int i = 0; i < V_LOOP; ++i) {
            int gi = lpv[i];
            sx += vb[gi * 3 + 0];
            sy += vb[gi * 3 + 1];
            sz += vb[gi * 3 + 2];
        }
        const float inv = 1.0f / (float)V_LOOP;
        if (tid == 0) {
            pts[V_HAND][0] = sx * inv; pts[V_HAND][1] = sy * inv; pts[V_HAND][2] = sz * inv;
        } else {
            ov[V_HAND][0] = sx * inv; ov[V_HAND][1] = sy * inv; ov[V_HAND][2] = sz * inv;
        }
    }
    for (int i = tid; i < N_FACES * 3; i += 256) fc[i] = fcs[i];
    __syncthreads();

    float wsum = 0.0f;
    float d2min = 1e30f;
    if (p < NPTS) {
        const float px = pts[p][0], py = pts[p][1], pz = pts[p][2];

        // Partial winding sum over faces k, k+8, ...
        for (int f = k; f < N_FACES; f += KSPLIT) {
            int i0 = fc[f * 3 + 0], i1 = fc[f * 3 + 1], i2 = fc[f * 3 + 2];
            float ax = ov[i0][0] - px, ay = ov[i0][1] - py, az = ov[i0][2] - pz;
            float bx = ov[i1][0] - px, by = ov[i1][1] - py, bz = ov[i1][2] - pz;
            float cx = ov[i2][0] - px, cy = ov[i2][1] - py, cz = ov[i2][2] - pz;

            float la = sqrtf(ax * ax + ay * ay + az * az);
            float lb = sqrtf(bx * bx + by * by + bz * bz);
            float lc = sqrtf(cx * cx + cy * cy + cz * cz);

            float ux = by * cz - bz * cy;
            float uy = bz * cx - bx * cz;
            float uz = bx * cy - by * cx;
            float det = ax * ux + ay * uy + az * uz;

            float ab = ax * bx + ay * by + az * bz;
            float bc = bx * cx + by * cy + bz * cz;
            float ca = cx * ax + cy * ay + cz * az;

            float denom = la * lb * lc + ab * lc + bc * la + ca * lb;
            wsum += atan2f(det, denom);
        }

        // Partial min-dist over verts k, k+8, ...
        for (int j = k; j < NPTS; j += KSPLIT) {
            float dx = ov[j][0] - px, dy = ov[j][1] - py, dz = ov[j][2] - pz;
            float d2 = dx * dx + dy * dy + dz * dz;
            d2min = fminf(d2min, d2);
        }
    }

    // Reduce across the 8-lane group (lanes p*8 .. p*8+7, wave-aligned)
    wsum  += __shfl_xor(wsum, 1);
    wsum  += __shfl_xor(wsum, 2);
    wsum  += __shfl_xor(wsum, 4);
    d2min = fminf(d2min, __shfl_xor(d2min, 1));
    d2min = fminf(d2min, __shfl_xor(d2min, 2));
    d2min = fminf(d2min, __shfl_xor(d2min, 4));

    float contrib = 0.0f;
    if (k == 0 && p < NPTS && wsum > (float)M_PI)
        contrib = sqrtf(d2min + 1e-12f);

    // Block reduction: wave64 shuffle then 4 partials in LDS
    for (int off = 32; off > 0; off >>= 1)
        contrib += __shfl_down(contrib, off);
    if ((tid & 63) == 0) wave_part[tid >> 6] = contrib;
    __syncthreads();
    if (tid == 0)
        partial[(b * 2 + dir) * NCHUNK + z] =
            wave_part[0] + wave_part[1] + wave_part[2] + wave_part[3];
}

__global__ void combine_kernel(const float* __restrict__ partial, float* __restrict__ out)
{
    int i = threadIdx.x;
    if (i < NB) {
        float s = 0.0f;
        for (int j = 0; j < 2 * NCHUNK; ++j)
            s += partial[i * 2 * NCHUNK + j];
        out[i] = s;
    }
}

extern "C" void kernel_launch(void* const* d_in, const int* in_sizes, int n_in,
                              void* d_out, int out_size, void* d_ws, size_t ws_size,
                              hipStream_t stream) {
    const float* verts  = (const float*)d_in[0];
    const int* inds_l   = (const int*)d_in[1];
    const int* inds_r   = (const int*)d_in[2];
    const int* loop_l   = (const int*)d_in[3];
    const int* loop_r   = (const int*)d_in[4];
    const int* faces_l  = (const int*)d_in[5];
    const int* faces_r  = (const int*)d_in[6];
    float* out = (float*)d_out;
    float* partial = (float*)d_ws;  // NB*2*NCHUNK floats

    hand_pen_kernel<<<dim3(NB, 2, NCHUNK), 256, 0, stream>>>(
        verts, inds_l, inds_r, loop_l, loop_r, faces_l, faces_r, partial);
    combine_kernel<<<1, 64, 0, stream>>>(partial, out);
}

// Round 3
// 52.940 us; speedup vs baseline: 3.8571x; 1.4408x over previous
//
#include <hip/hip_runtime.h>
#include <math.h>

#define NB 64
#define V_FULL 6890
#define V_HAND 250
#define V_LOOP 20
#define N_FACES 500
#define NPTS 251      // V_HAND + 1 (appended loop-mean vertex)
#define KSPLIT 16     // lanes per point (face-loop split)
#define PCHUNK 16     // points per block
#define NCHUNK 16     // ceil(251/16)

// Branchless fast atan2: rcp-based division, Cephes range reduction
// (|z| <= tan(pi/8)) + degree-9 odd minimax poly. Max err ~3e-7 rad.
__device__ __forceinline__ float fast_atan2f(float y, float x) {
    const float PI   = 3.14159265358979f;
    const float PIO2 = 1.57079632679490f;
    const float PIO4 = 0.78539816339745f;
    float ay = __builtin_fabsf(y), ax = __builtin_fabsf(x);
    float mx = fmaxf(ax, ay), mn = fminf(ax, ay);
    float t  = mn * __builtin_amdgcn_rcpf(fmaxf(mx, 1e-38f));  // [0,1]
    bool  hi = t > 0.4142135624f;
    float z  = hi ? (t - 1.0f) * __builtin_amdgcn_rcpf(t + 1.0f) : t;
    float z2 = z * z;
    float p  = fmaf(8.05374449538e-2f, z2, -1.38776856032e-1f);
    p = fmaf(p, z2, 1.99777106478e-1f);
    p = fmaf(p, z2, -3.33329491539e-1f);
    float r = fmaf(z2 * z, p, z);
    r += hi ? PIO4 : 0.0f;
    if (ay > ax)  r = PIO2 - r;
    if (x < 0.0f) r = PI - r;
    return copysignf(r, y);
}

// Grid (NB, 2, NCHUNK). Block 256 = PCHUNK points x KSPLIT lanes.
// dir 0: points = left-hand verts, other = right, faces = faces_right
// dir 1: points = right-hand verts, other = left,  faces = faces_left
__global__ __launch_bounds__(256) void hand_pen_kernel(
    const float* __restrict__ verts,     // [NB][V_FULL][3]
    const int* __restrict__ inds_l,
    const int* __restrict__ inds_r,
    const int* __restrict__ loop_l,
    const int* __restrict__ loop_r,
    const int* __restrict__ faces_l,     // [N_FACES][3]
    const int* __restrict__ faces_r,
    float* __restrict__ partial)         // [NB][2][NCHUNK]
{
    const int b   = blockIdx.x;
    const int dir = blockIdx.y;
    const int z   = blockIdx.z;
    const int tid = threadIdx.x;
    const int lp  = tid >> 4;           // local point 0..15
    const int k   = tid & 15;           // split lane 0..15
    int p = z * PCHUNK + lp;
    const bool valid = (p < NPTS);
    if (!valid) p = NPTS - 1;           // clamp; contribution masked later

    __shared__ float  pts[NPTS][3];
    __shared__ float4 ov4[NPTS];        // padded for ds_read_b128
    __shared__ int4   fc4[N_FACES];     // padded for ds_read_b128
    __shared__ float  wave_part[4];

    const float* vb = verts + (size_t)b * V_FULL * 3;
    const int* pind  = (dir == 0) ? inds_l  : inds_r;
    const int* oind  = (dir == 0) ? inds_r  : inds_l;
    const int* ploop = (dir == 0) ? loop_l  : loop_r;
    const int* oloop = (dir == 0) ? loop_r  : loop_l;
    const int* fcs   = (dir == 0) ? faces_r : faces_l;

    for (int i = tid; i < V_HAND; i += 256) {
        int gp = pind[i];
        pts[i][0] = vb[gp * 3 + 0];
        pts[i][1] = vb[gp * 3 + 1];
        pts[i][2] = vb[gp * 3 + 2];
        int go = oind[i];
        ov4[i] = make_float4(vb[go * 3 + 0], vb[go * 3 + 1], vb[go * 3 + 2], 0.0f);
    }
    if (tid < 2) {
        const int* lpv = (tid == 0) ? ploop : oloop;
        float sx = 0.f, sy = 0.f, sz = 0.f;
        for (int i = 0; i < V_LOOP; ++i) {
            int gi = lpv[i];
            sx += vb[gi * 3 + 0];
            sy += vb[gi * 3 + 1];
            sz += vb[gi * 3 + 2];
        }
        const float inv = 1.0f / (float)V_LOOP;
        if (tid == 0) {
            pts[V_HAND][0] = sx * inv; pts[V_HAND][1] = sy * inv; pts[V_HAND][2] = sz * inv;
        } else {
            ov4[V_HAND] = make_float4(sx * inv, sy * inv, sz * inv, 0.0f);
        }
    }
    for (int i = tid; i < N_FACES; i += 256) {
        fc4[i] = make_int4(fcs[3 * i + 0], fcs[3 * i + 1], fcs[3 * i + 2], 0);
    }
    __syncthreads();

    const float px = pts[p][0], py = pts[p][1], pz = pts[p][2];

    // Partial winding sum over faces k, k+16, ...
    float wsum = 0.0f;
    for (int f = k; f < N_FACES; f += KSPLIT) {
        int4 fi = fc4[f];
        float4 va = ov4[fi.x];
        float4 vbq = ov4[fi.y];
        float4 vc = ov4[fi.z];
        float ax = va.x - px,  ay = va.y - py,  az = va.z - pz;
        float bx = vbq.x - px, by = vbq.y - py, bz = vbq.z - pz;
        float cx = vc.x - px,  cy = vc.y - py,  cz = vc.z - pz;

        float la = __builtin_amdgcn_sqrtf(ax * ax + ay * ay + az * az);
        float lb = __builtin_amdgcn_sqrtf(bx * bx + by * by + bz * bz);
        float lc = __builtin_amdgcn_sqrtf(cx * cx + cy * cy + cz * cz);

        float ux = by * cz - bz * cy;
        float uy = bz * cx - bx * cz;
        float uz = bx * cy - by * cx;
        float det = ax * ux + ay * uy + az * uz;

        float ab = ax * bx + ay * by + az * bz;
        float bc = bx * cx + by * cy + bz * cz;
        float ca = cx * ax + cy * ay + cz * az;

        float denom = la * lb * lc + ab * lc + bc * la + ca * lb;
        wsum += fast_atan2f(det, denom);
    }

    // Partial min-dist over verts k, k+16, ...
    float d2min = 1e30f;
    for (int j = k; j < NPTS; j += KSPLIT) {
        float4 v = ov4[j];
        float dx = v.x - px, dy = v.y - py, dz = v.z - pz;
        float d2 = dx * dx + dy * dy + dz * dz;
        d2min = fminf(d2min, d2);
    }

    // Reduce across the 16-lane group (wave-aligned)
    wsum += __shfl_xor(wsum, 1);
    wsum += __shfl_xor(wsum, 2);
    wsum += __shfl_xor(wsum, 4);
    wsum += __shfl_xor(wsum, 8);
    d2min = fminf(d2min, __shfl_xor(d2min, 1));
    d2min = fminf(d2min, __shfl_xor(d2min, 2));
    d2min = fminf(d2min, __shfl_xor(d2min, 4));
    d2min = fminf(d2min, __shfl_xor(d2min, 8));

    float contrib = 0.0f;
    if (k == 0 && valid && wsum > (float)M_PI)
        contrib = __builtin_amdgcn_sqrtf(d2min + 1e-12f);

    // Block reduction: wave64 shuffle then 4 partials in LDS
    for (int off = 32; off > 0; off >>= 1)
        contrib += __shfl_down(contrib, off);
    if ((tid & 63) == 0) wave_part[tid >> 6] = contrib;
    __syncthreads();
    if (tid == 0)
        partial[(b * 2 + dir) * NCHUNK + z] =
            wave_part[0] + wave_part[1] + wave_part[2] + wave_part[3];
}

__global__ void combine_kernel(const float* __restrict__ partial, float* __restrict__ out)
{
    int i = threadIdx.x;
    if (i < NB) {
        float s = 0.0f;
        for (int j = 0; j < 2 * NCHUNK; ++j)
            s += partial[i * 2 * NCHUNK + j];
        out[i] = s;
    }
}

extern "C" void kernel_launch(void* const* d_in, const int* in_sizes, int n_in,
                              void* d_out, int out_size, void* d_ws, size_t ws_size,
                              hipStream_t stream) {
    const float* verts  = (const float*)d_in[0];
    const int* inds_l   = (const int*)d_in[1];
    const int* inds_r   = (const int*)d_in[2];
    const int* loop_l   = (const int*)d_in[3];
    const int* loop_r   = (const int*)d_in[4];
    const int* faces_l  = (const int*)d_in[5];
    const int* faces_r  = (const int*)d_in[6];
    float* out = (float*)d_out;
    float* partial = (float*)d_ws;  // NB*2*NCHUNK floats

    hand_pen_kernel<<<dim3(NB, 2, NCHUNK), 256, 0, stream>>>(
        verts, inds_l, inds_r, loop_l, loop_r, faces_l, faces_r, partial);
    combine_kernel<<<1, 64, 0, stream>>>(partial, out);
}